// Round 4
// baseline (762.111 us; speedup 1.0000x reference)
//
#include <hip/hip_runtime.h>
#include <hip/hip_bf16.h>

// Transducer joint: logits[b,t,u,v] = tanh(enc_proj[b,t,:]+dec_proj[b,u,:]+b1) @ W2 + b2
// B=4 T=256 U=128, ENC=DEC=512, INNER=512, VOCAB=2048
// R4: tanh fused into the 256x256 8-phase GEMM's A-staging (computed ds_write,
//     swizzled); B via gl16 + counted vmcnt. No H materialization. GEMM HBM
//     traffic = output writes only.

typedef __attribute__((ext_vector_type(4))) float f32x4;
typedef __attribute__((ext_vector_type(8))) __bf16 bf16x8;
typedef __attribute__((ext_vector_type(8))) unsigned short u16x8;

__device__ __forceinline__ float bf2f(unsigned short u) {
  unsigned int x = ((unsigned int)u) << 16;
  return __builtin_bit_cast(float, x);
}
__device__ __forceinline__ unsigned short f2bf(float f) {
  unsigned int x = __builtin_bit_cast(unsigned int, f);
  x += 0x7fff + ((x >> 16) & 1);   // RNE
  return (unsigned short)(x >> 16);
}
__device__ __forceinline__ float tanh_fast(float x) {
  float e = __expf(2.0f * x);
  return 1.0f - 2.0f * __builtin_amdgcn_rcpf(e + 1.0f);
}

typedef __attribute__((address_space(3))) unsigned int lds_u32;
typedef const __attribute__((address_space(1))) unsigned int glb_u32;
__device__ __forceinline__ void gl16(const void* g, void* l) {
  __builtin_amdgcn_global_load_lds((glb_u32*)g, (lds_u32*)l, 16, 0, 0);
}

#define BAR __builtin_amdgcn_s_barrier()
#define LGKM0 asm volatile("s_waitcnt lgkmcnt(0)" ::: "memory")
#define VMCNT(n) asm volatile("s_waitcnt vmcnt(" #n ")" ::: "memory")
#define MEMPIN asm volatile("" ::: "memory")

// ---------------- Pass 1: proj (x-in-LDS broadcast GEMM) ----------------
// 192 blocks x 512 thr: bid<128 -> enc rows bid*8 (fp32 out); else dec rows
// (bid-128)*8 (+b1, bf16 out). Thread owns one h column, 8 row-accumulators.
__global__ __launch_bounds__(512) void proj8_kernel(
    const float* __restrict__ enc, const float* __restrict__ dec,
    const float* __restrict__ W1, const float* __restrict__ b1,
    float* __restrict__ enc_proj, unsigned short* __restrict__ decb) {
  __shared__ float xs[8][512];
  const int bid = blockIdx.x;
  const bool isenc = bid < 128;
  const int rows0 = (isenc ? bid : bid - 128) * 8;
  const float* src = (isenc ? enc : dec) + (size_t)rows0 * 512;
  const int tid = threadIdx.x;
#pragma unroll
  for (int j = 0; j < 2; ++j) {
    int v = j * 512 + tid;
    int row = v >> 7;
    int c4 = (v & 127) << 2;
    *(f32x4*)&xs[row][c4] = *(const f32x4*)&src[(size_t)row * 512 + c4];
  }
  __syncthreads();
  const int h = tid;
  const float* wp = W1 + (isenc ? 0 : (size_t)512 * 512) + h;
  float acc[8];
  float init = isenc ? 0.f : b1[h];
#pragma unroll
  for (int r = 0; r < 8; ++r) acc[r] = init;
#pragma unroll 4
  for (int k = 0; k < 512; ++k) {
    float wv = wp[(size_t)k * 512];
#pragma unroll
    for (int r = 0; r < 8; ++r) acc[r] = fmaf(xs[r][k], wv, acc[r]);
  }
  if (isenc) {
#pragma unroll
    for (int r = 0; r < 8; ++r) enc_proj[(size_t)(rows0 + r) * 512 + h] = acc[r];
  } else {
#pragma unroll
    for (int r = 0; r < 8; ++r) decb[(size_t)(rows0 + r) * 512 + h] = f2bf(acc[r]);
  }
}

// ---------------- Pass 2: W2 [512][2048] fp32 -> W2t [2048][512] bf16 ----------------
__global__ __launch_bounds__(256) void w2t_kernel(const float* __restrict__ W2,
                                                  unsigned short* __restrict__ W2t) {
  __shared__ unsigned short tile[32][33];
  int bn = blockIdx.x;
  int bk = blockIdx.y;
  int tx = threadIdx.x & 31;
  int ty = threadIdx.x >> 5;
#pragma unroll
  for (int i = 0; i < 32; i += 8)
    tile[ty + i][tx] = f2bf(W2[(size_t)(bk * 32 + ty + i) * 2048 + bn * 32 + tx]);
  __syncthreads();
#pragma unroll
  for (int i = 0; i < 32; i += 8)
    W2t[(size_t)(bn * 32 + ty + i) * 512 + bk * 32 + tx] = tile[tx][ty + i];
}

// ---------------- Pass 3: fused 256x256 8-phase GEMM ----------------
// A-tile = tanh(encp + decb) computed in-kernel into swizzled LDS (dbuf A0/A1);
// B staged via gl16 (dbuf B0/B1, counted vmcnt: only B loads occupy vmcnt).
// Tile ledger: prologue A0<-t0,A1<-t1,B0<-t0,B1<-t1 (full drain).
// iter i (t=2i): ph1,2 stage A(t+1)->A1 (i>=1); ph3,4 stage B(t+2)->B0 (i<=2);
// ph4,5 stage A(t+2)->A0 (i<=2); ph7,8 stage B(t+3)->B1 (i<=2).
// VMCNT(4) at ph4 (retires prev ph7,8 -> B1 ready for ph5) and ph8 (retires
// ph3,4 -> B0 ready for next ph1); final iter uses VMCNT(0).

__device__ __forceinline__ void stage_b(const char* src, char* dst_region,
                                        int half, int w, int lane) {
#pragma unroll
  for (int r = 0; r < 2; ++r) {
    int dbase = half * 16384 + r * 8192 + w * 1024;
    int d = dbase + lane * 16;
    int s = d ^ (((d >> 9) & 1) << 5);
    gl16(src + (size_t)(s >> 7) * 1024 + (s & 127), dst_region + dbase);
  }
}

// compute 16 tanh elems and ds_write (swizzled) one 128-row half of an A-tile
__device__ __forceinline__ void stage_a_tanh(const float* encrow,
                                             const unsigned short* decbase,
                                             char* Areg, int half, int t, int tid) {
  const int row_l = tid >> 2;          // 0..127
  const int kq = (tid & 3) << 4;       // 0,16,32,48
  const int koff = t * 64 + kq;
  const unsigned short* dp = decbase + (size_t)row_l * 512 + koff;
  u16x8 d0 = *(const u16x8*)dp;
  u16x8 d1 = *(const u16x8*)(dp + 8);
  f32x4 e0 = *(const f32x4*)(encrow + koff);
  f32x4 e1 = *(const f32x4*)(encrow + koff + 4);
  f32x4 e2 = *(const f32x4*)(encrow + koff + 8);
  f32x4 e3 = *(const f32x4*)(encrow + koff + 12);
  u16x8 h0, h1;
#pragma unroll
  for (int j = 0; j < 4; ++j) h0[j] = f2bf(tanh_fast(bf2f(d0[j]) + e0[j]));
#pragma unroll
  for (int j = 0; j < 4; ++j) h0[4 + j] = f2bf(tanh_fast(bf2f(d0[4 + j]) + e1[j]));
#pragma unroll
  for (int j = 0; j < 4; ++j) h1[j] = f2bf(tanh_fast(bf2f(d1[j]) + e2[j]));
#pragma unroll
  for (int j = 0; j < 4; ++j) h1[4 + j] = f2bf(tanh_fast(bf2f(d1[4 + j]) + e3[j]));
  const int r = half * 128 + row_l;
  const int d = r * 128 + kq * 2;
  const int x = ((r >> 2) & 1) << 5;   // st_16x32: bit9 of byte-offset -> bit5
  *(u16x8*)(Areg + (d ^ x)) = h0;
  *(u16x8*)(Areg + ((d + 16) ^ x)) = h1;
}

__device__ __forceinline__ void load_a(const char* Ar, int a_base, int MH,
                                       bf16x8 (&afr)[4][2]) {
#pragma unroll
  for (int mi = 0; mi < 4; ++mi)
#pragma unroll
    for (int kk = 0; kk < 2; ++kk)
      afr[mi][kk] = *(const bf16x8*)(Ar + a_base + MH * 8192 + mi * 2048 + kk * 64);
}
__device__ __forceinline__ void load_b(const char* Br, int b_base, int NH,
                                       bf16x8 (&bh)[2][2]) {
#pragma unroll
  for (int ni = 0; ni < 2; ++ni)
#pragma unroll
    for (int kk = 0; kk < 2; ++kk)
      bh[ni][kk] = *(const bf16x8*)(Br + b_base + NH * 4096 + ni * 2048 + kk * 64);
}

template <int MH, int NH>
__device__ __forceinline__ void mfma_quad(bf16x8 (&afr)[4][2], bf16x8 (&bh)[2][2],
                                          f32x4 (&acc)[8][4]) {
  __builtin_amdgcn_s_setprio(1);
#pragma unroll
  for (int mi = 0; mi < 4; ++mi)
#pragma unroll
    for (int ni = 0; ni < 2; ++ni)
#pragma unroll
      for (int kk = 0; kk < 2; ++kk)
        acc[MH * 4 + mi][NH * 2 + ni] = __builtin_amdgcn_mfma_f32_16x16x32_bf16(
            afr[mi][kk], bh[ni][kk], acc[MH * 4 + mi][NH * 2 + ni], 0, 0, 0);
  __builtin_amdgcn_s_setprio(0);
}

__global__ __launch_bounds__(512, 2) void gemm8f_kernel(
    const float* __restrict__ encp,           // [1024][512] f32
    const unsigned short* __restrict__ decb,  // [512][512] bf16 (b1 folded)
    const unsigned short* __restrict__ W2t,   // [2048][512] bf16
    const float* __restrict__ b2,             // [2048]
    float* __restrict__ out) {                // [131072][2048] fp32
  __shared__ __align__(1024) char smem[131072];
  char* A0 = smem;
  char* B0 = smem + 32768;
  char* A1 = smem + 65536;
  char* B1 = smem + 98304;

  const int bid = blockIdx.x;
  const int wg = (bid & 7) * 512 + (bid >> 3);   // 4096%8==0 -> bijective
  const int my = wg >> 3;    // 0..511: A panel (rows my*256..), 8 wg share it
  const int ny = wg & 7;     // 0..7:   N block

  const int tid = threadIdx.x;
  const int lane = tid & 63;
  const int w = tid >> 6;
  const int wm = w >> 2;
  const int wn = w & 3;
  const int fr = lane & 15;
  const int fq = lane >> 4;
  const int xr = (fr & 4) ? 32 : 0;

  // A sources: rows my*256+r, r<128 -> bt0=2*my, r>=128 -> bt1=2*my+1; u=r&127
  const float* enc0 = encp + (size_t)(2 * my) * 512;
  const float* enc1 = enc0 + 512;
  const unsigned short* db = decb + (size_t)(my >> 7) * 128 * 512;  // b = my>>7
  const char* wb = (const char*)(W2t + (size_t)ny * 256 * 512);

  const int a_base = (wm * 128 + fr) * 128 + ((fq * 16) ^ xr);
  const int b_base = (wn * 64 + fr) * 128 + ((fq * 16) ^ xr);

  f32x4 acc[8][4];
#pragma unroll
  for (int i = 0; i < 8; ++i)
#pragma unroll
    for (int j = 0; j < 4; ++j) acc[i][j] = (f32x4){0.f, 0.f, 0.f, 0.f};
  bf16x8 afr[4][2];
  bf16x8 bfr[2][2][2];

  // ---- prologue: B0<-t0, B1<-t1 (gl16, issued first); A0<-t0, A1<-t1 (tanh) ----
  stage_b(wb, B0, 0, w, lane);        stage_b(wb, B0, 1, w, lane);
  stage_b(wb + 128, B1, 0, w, lane);  stage_b(wb + 128, B1, 1, w, lane);
  stage_a_tanh(enc0, db, A0, 0, 0, tid);
  stage_a_tanh(enc1, db, A0, 1, 0, tid);
  stage_a_tanh(enc0, db, A1, 0, 1, tid);
  stage_a_tanh(enc1, db, A1, 1, 1, tid);
  LGKM0; VMCNT(0);
  BAR; MEMPIN;

  for (int i = 0; i < 4; ++i) {
    const int t = 2 * i;
    const char* sB2 = wb + (size_t)(t + 2) * 128;
    const char* sB3 = wb + (size_t)(t + 3) * 128;
    const bool si = (i >= 1);
    const bool so = (i <= 2);

    // ph1: read A0.MH0,B0.NH0; stage A(t+1)h0 -> A1
    load_a(A0, a_base, 0, afr);
    load_b(B0, b_base, 0, bfr[0]);
    if (si) stage_a_tanh(enc0, db, A1, 0, t + 1, tid);
    LGKM0; BAR;
    mfma_quad<0, 0>(afr, bfr[0], acc);
    BAR; MEMPIN;

    // ph2: read B0.NH1; stage A(t+1)h1 -> A1
    load_b(B0, b_base, 1, bfr[1]);
    if (si) stage_a_tanh(enc1, db, A1, 1, t + 1, tid);
    LGKM0; BAR;
    mfma_quad<0, 1>(afr, bfr[1], acc);
    BAR; MEMPIN;

    // ph3: read A0.MH1; stage B(t+2)h0 -> B0
    load_a(A0, a_base, 1, afr);
    if (so) stage_b(sB2, B0, 0, w, lane);
    LGKM0; BAR;
    mfma_quad<1, 0>(afr, bfr[0], acc);
    BAR; MEMPIN;

    // ph4: stage B(t+2)h1 -> B0, A(t+2)h0 -> A0; vmcnt gates B1 for ph5
    if (so) {
      stage_b(sB2, B0, 1, w, lane);
      stage_a_tanh(enc0, db, A0, 0, t + 2, tid);
    }
    LGKM0; BAR;
    mfma_quad<1, 1>(afr, bfr[1], acc);
    if (i < 3) { VMCNT(4); } else { VMCNT(0); }
    BAR; MEMPIN;

    // ph5: read A1.MH0,B1.NH0; stage A(t+2)h1 -> A0
    load_a(A1, a_base, 0, afr);
    load_b(B1, b_base, 0, bfr[0]);
    if (so) stage_a_tanh(enc1, db, A0, 1, t + 2, tid);
    LGKM0; BAR;
    mfma_quad<0, 0>(afr, bfr[0], acc);
    BAR; MEMPIN;

    // ph6: read B1.NH1
    load_b(B1, b_base, 1, bfr[1]);
    LGKM0; BAR;
    mfma_quad<0, 1>(afr, bfr[1], acc);
    BAR; MEMPIN;

    // ph7: read A1.MH1; stage B(t+3)h0 -> B1
    load_a(A1, a_base, 1, afr);
    if (so) stage_b(sB3, B1, 0, w, lane);
    LGKM0; BAR;
    mfma_quad<1, 0>(afr, bfr[0], acc);
    BAR; MEMPIN;

    // ph8: stage B(t+3)h1 -> B1; vmcnt gates B0 for next ph1
    if (so) stage_b(sB3, B1, 1, w, lane);
    LGKM0; BAR;
    mfma_quad<1, 1>(afr, bfr[1], acc);
    if (i < 3) { VMCNT(4); } else { VMCNT(0); }
    BAR; MEMPIN;
  }

  // ---- epilogue: +b2, fp32 store ----
  const int ccol = fr;
  const int crow = fq * 4;
  const size_t orow0 = (size_t)my * 256 + wm * 128;
  const int ncol0 = ny * 256 + wn * 64;
#pragma unroll
  for (int ni4 = 0; ni4 < 4; ++ni4) {
    int n = ncol0 + ni4 * 16 + ccol;
    float bv = b2[n];
#pragma unroll
    for (int mi8 = 0; mi8 < 8; ++mi8) {
      size_t r0 = orow0 + (size_t)mi8 * 16 + crow;
#pragma unroll
      for (int r = 0; r < 4; ++r)
        out[(r0 + r) * 2048 + n] = acc[mi8][ni4][r] + bv;
    }
  }
}

extern "C" void kernel_launch(void* const* d_in, const int* in_sizes, int n_in,
                              void* d_out, int out_size, void* d_ws, size_t ws_size,
                              hipStream_t stream) {
  const float* enc = (const float*)d_in[0];
  const float* dec = (const float*)d_in[1];
  const float* W1  = (const float*)d_in[2];
  const float* b1  = (const float*)d_in[3];
  const float* W2  = (const float*)d_in[4];
  const float* b2  = (const float*)d_in[5];
  float* out = (float*)d_out;

  char* ws = (char*)d_ws;
  float* enc_proj = (float*)ws;                                    // 2 MB
  unsigned short* decb = (unsigned short*)(ws + (2u << 20));       // 512 KB
  unsigned short* W2t  = (unsigned short*)(ws + (2u << 20) + (512u << 10)); // 2 MB

  proj8_kernel<<<192, 512, 0, stream>>>(enc, dec, W1, b1, enc_proj, decb);
  w2t_kernel<<<dim3(64, 16), 256, 0, stream>>>(W2, W2t);
  gemm8f_kernel<<<4096, 512, 0, stream>>>(enc_proj, decb, W2t, b2, out);
}

// Round 5
// 427.006 us; speedup vs baseline: 1.7848x; 1.7848x over previous
//
#include <hip/hip_runtime.h>
#include <hip/hip_bf16.h>

// Transducer joint: logits[b,t,u,v] = tanh(enc_proj[b,t,:]+dec_proj[b,u,:]+b1) @ W2 + b2
// B=4 T=256 U=128, ENC=DEC=512, INNER=512, VOCAB=2048
// R5: de-fused (H materialized bf16) + 256x256 8-phase GEMM (R3 schedule) +
//     non-temporal full-line epilogue stores via per-wave LDS transpose.

typedef __attribute__((ext_vector_type(4))) float f32x4;
typedef __attribute__((ext_vector_type(8))) __bf16 bf16x8;
typedef __attribute__((ext_vector_type(8))) unsigned short u16x8;

__device__ __forceinline__ float bf2f(unsigned short u) {
  unsigned int x = ((unsigned int)u) << 16;
  return __builtin_bit_cast(float, x);
}
__device__ __forceinline__ unsigned short f2bf(float f) {
  unsigned int x = __builtin_bit_cast(unsigned int, f);
  x += 0x7fff + ((x >> 16) & 1);   // RNE
  return (unsigned short)(x >> 16);
}
__device__ __forceinline__ float tanh_fast(float x) {
  float e = __expf(2.0f * x);
  return 1.0f - 2.0f * __builtin_amdgcn_rcpf(e + 1.0f);
}

typedef __attribute__((address_space(3))) unsigned int lds_u32;
typedef const __attribute__((address_space(1))) unsigned int glb_u32;
__device__ __forceinline__ void gl16(const void* g, void* l) {
  __builtin_amdgcn_global_load_lds((glb_u32*)g, (lds_u32*)l, 16, 0, 0);
}

#define BAR __builtin_amdgcn_s_barrier()
#define LGKM0 asm volatile("s_waitcnt lgkmcnt(0)" ::: "memory")
#define VMCNT(n) asm volatile("s_waitcnt vmcnt(" #n ")" ::: "memory")
#define MEMPIN asm volatile("" ::: "memory")

// ---------------- Pass 1: proj (x-in-LDS broadcast GEMM) ----------------
__global__ __launch_bounds__(512) void proj8_kernel(
    const float* __restrict__ enc, const float* __restrict__ dec,
    const float* __restrict__ W1, const float* __restrict__ b1,
    float* __restrict__ enc_proj, unsigned short* __restrict__ decb) {
  __shared__ float xs[8][512];
  const int bid = blockIdx.x;
  const bool isenc = bid < 128;
  const int rows0 = (isenc ? bid : bid - 128) * 8;
  const float* src = (isenc ? enc : dec) + (size_t)rows0 * 512;
  const int tid = threadIdx.x;
#pragma unroll
  for (int j = 0; j < 2; ++j) {
    int v = j * 512 + tid;
    int row = v >> 7;
    int c4 = (v & 127) << 2;
    *(f32x4*)&xs[row][c4] = *(const f32x4*)&src[(size_t)row * 512 + c4];
  }
  __syncthreads();
  const int h = tid;
  const float* wp = W1 + (isenc ? 0 : (size_t)512 * 512) + h;
  float acc[8];
  float init = isenc ? 0.f : b1[h];
#pragma unroll
  for (int r = 0; r < 8; ++r) acc[r] = init;
#pragma unroll 4
  for (int k = 0; k < 512; ++k) {
    float wv = wp[(size_t)k * 512];
#pragma unroll
    for (int r = 0; r < 8; ++r) acc[r] = fmaf(xs[r][k], wv, acc[r]);
  }
  if (isenc) {
#pragma unroll
    for (int r = 0; r < 8; ++r) enc_proj[(size_t)(rows0 + r) * 512 + h] = acc[r];
  } else {
#pragma unroll
    for (int r = 0; r < 8; ++r) decb[(size_t)(rows0 + r) * 512 + h] = f2bf(acc[r]);
  }
}

// ---------------- Pass 2: W2 [512][2048] fp32 -> W2t [2048][512] bf16 ----------------
__global__ __launch_bounds__(256) void w2t_kernel(const float* __restrict__ W2,
                                                  unsigned short* __restrict__ W2t) {
  __shared__ unsigned short tile[32][33];
  int bn = blockIdx.x;
  int bk = blockIdx.y;
  int tx = threadIdx.x & 31;
  int ty = threadIdx.x >> 5;
#pragma unroll
  for (int i = 0; i < 32; i += 8)
    tile[ty + i][tx] = f2bf(W2[(size_t)(bk * 32 + ty + i) * 2048 + bn * 32 + tx]);
  __syncthreads();
#pragma unroll
  for (int i = 0; i < 32; i += 8)
    W2t[(size_t)(bn * 32 + ty + i) * 512 + bk * 32 + tx] = tile[tx][ty + i];
}

// ---------------- Pass 3: H[m][h] = tanh(encp[bt][h] + decb[bu][h]) bf16 ----------------
__global__ __launch_bounds__(256) void h_kernel(
    const float* __restrict__ encp, const unsigned short* __restrict__ decb,
    unsigned short* __restrict__ Hout) {
  int gid = blockIdx.x * 256 + threadIdx.x;
  int m = gid >> 6;
  int hc = (gid & 63) << 3;
  int bt = m >> 7;
  int bu = ((m >> 15) << 7) | (m & 127);
  u16x8 dv = *(const u16x8*)(decb + (size_t)bu * 512 + hc);
  f32x4 e0 = *(const f32x4*)(encp + (size_t)bt * 512 + hc);
  f32x4 e1 = *(const f32x4*)(encp + (size_t)bt * 512 + hc + 4);
  u16x8 hv;
#pragma unroll
  for (int j = 0; j < 4; ++j) hv[j] = f2bf(tanh_fast(bf2f(dv[j]) + e0[j]));
#pragma unroll
  for (int j = 0; j < 4; ++j) hv[4 + j] = f2bf(tanh_fast(bf2f(dv[4 + j]) + e1[j]));
  *(u16x8*)(Hout + (size_t)m * 512 + hc) = hv;
}

// ---------------- Pass 4: 256x256 8-phase GEMM (R3 schedule, nt epilogue) ----------------
__device__ __forceinline__ void stage_half(const char* src, char* dst_region,
                                           int half, int w, int lane) {
#pragma unroll
  for (int r = 0; r < 2; ++r) {
    int dbase = half * 16384 + r * 8192 + w * 1024;
    int d = dbase + lane * 16;
    int s = d ^ (((d >> 9) & 1) << 5);
    gl16(src + (size_t)(s >> 7) * 1024 + (s & 127), dst_region + dbase);
  }
}

__device__ __forceinline__ void load_a(const char* Ar, int a_base, int MH,
                                       bf16x8 (&afr)[4][2]) {
#pragma unroll
  for (int mi = 0; mi < 4; ++mi)
#pragma unroll
    for (int kk = 0; kk < 2; ++kk)
      afr[mi][kk] = *(const bf16x8*)(Ar + a_base + MH * 8192 + mi * 2048 + kk * 64);
}
__device__ __forceinline__ void load_b(const char* Br, int b_base, int NH,
                                       bf16x8 (&bh)[2][2]) {
#pragma unroll
  for (int ni = 0; ni < 2; ++ni)
#pragma unroll
    for (int kk = 0; kk < 2; ++kk)
      bh[ni][kk] = *(const bf16x8*)(Br + b_base + NH * 4096 + ni * 2048 + kk * 64);
}

template <int MH, int NH>
__device__ __forceinline__ void mfma_quad(bf16x8 (&afr)[4][2], bf16x8 (&bh)[2][2],
                                          f32x4 (&acc)[8][4]) {
  __builtin_amdgcn_s_setprio(1);
#pragma unroll
  for (int mi = 0; mi < 4; ++mi)
#pragma unroll
    for (int ni = 0; ni < 2; ++ni)
#pragma unroll
      for (int kk = 0; kk < 2; ++kk)
        acc[MH * 4 + mi][NH * 2 + ni] = __builtin_amdgcn_mfma_f32_16x16x32_bf16(
            afr[mi][kk], bh[ni][kk], acc[MH * 4 + mi][NH * 2 + ni], 0, 0, 0);
  __builtin_amdgcn_s_setprio(0);
}

__global__ __launch_bounds__(512, 2) void gemm8_kernel(
    const unsigned short* __restrict__ H,     // [131072][512] bf16
    const unsigned short* __restrict__ W2t,   // [2048][512] bf16
    const float* __restrict__ b2,             // [2048]
    float* __restrict__ out) {                // [131072][2048] fp32
  __shared__ __align__(1024) char smem[131072];
  char* A0 = smem;
  char* B0 = smem + 32768;
  char* A1 = smem + 65536;
  char* B1 = smem + 98304;

  const int bid = blockIdx.x;
  const int wg = (bid & 7) * 512 + (bid >> 3);   // 4096%8==0 -> bijective
  const int my = wg >> 3;    // 0..511
  const int ny = wg & 7;     // 0..7

  const int tid = threadIdx.x;
  const int lane = tid & 63;
  const int w = tid >> 6;
  const int wm = w >> 2;
  const int wn = w & 3;
  const int fr = lane & 15;
  const int fq = lane >> 4;
  const int xr = (fr & 4) ? 32 : 0;

  const char* ha = (const char*)(H + (size_t)my * 256 * 512);
  const char* wb = (const char*)(W2t + (size_t)ny * 256 * 512);

  const int a_base = (wm * 128 + fr) * 128 + ((fq * 16) ^ xr);
  const int b_base = (wn * 64 + fr) * 128 + ((fq * 16) ^ xr);

  f32x4 acc[8][4];
#pragma unroll
  for (int i = 0; i < 8; ++i)
#pragma unroll
    for (int j = 0; j < 4; ++j) acc[i][j] = (f32x4){0.f, 0.f, 0.f, 0.f};
  bf16x8 afr[4][2];
  bf16x8 bfr[2][2][2];

  // ---- prologue ----
  stage_half(ha, A0, 0, w, lane);        stage_half(ha, A0, 1, w, lane);
  stage_half(wb, B0, 0, w, lane);        stage_half(wb, B0, 1, w, lane);
  stage_half(ha + 128, A1, 0, w, lane);  stage_half(ha + 128, A1, 1, w, lane);
  stage_half(wb + 128, B1, 0, w, lane);  stage_half(wb + 128, B1, 1, w, lane);
  VMCNT(0);
  BAR; MEMPIN;

  for (int i = 0; i < 4; ++i) {
    const int t = 2 * i;
    const char* sA1 = ha + (size_t)(t + 1) * 128;
    const char* sA2 = ha + (size_t)(t + 2) * 128;
    const char* sB2 = wb + (size_t)(t + 2) * 128;
    const char* sB3 = wb + (size_t)(t + 3) * 128;
    const bool si = (i >= 1);
    const bool so = (i <= 2);

    load_a(A0, a_base, 0, afr);
    load_b(B0, b_base, 0, bfr[0]);
    if (si) stage_half(sA1, A1, 0, w, lane);
    BAR; LGKM0;
    mfma_quad<0, 0>(afr, bfr[0], acc);
    BAR; MEMPIN;

    load_b(B0, b_base, 1, bfr[1]);
    if (si) stage_half(sA1, A1, 1, w, lane);
    BAR; LGKM0;
    mfma_quad<0, 1>(afr, bfr[1], acc);
    BAR; MEMPIN;

    load_a(A0, a_base, 1, afr);
    if (so) stage_half(sB2, B0, 0, w, lane);
    BAR; LGKM0;
    mfma_quad<1, 0>(afr, bfr[0], acc);
    BAR; MEMPIN;

    if (so) {
      stage_half(sB2, B0, 1, w, lane);
      stage_half(sA2, A0, 0, w, lane);
      stage_half(sA2, A0, 1, w, lane);
    }
    BAR; LGKM0;
    mfma_quad<1, 1>(afr, bfr[1], acc);
    if (i < 3) { VMCNT(8); } else { VMCNT(0); }
    BAR; MEMPIN;

    load_a(A1, a_base, 0, afr);
    load_b(B1, b_base, 0, bfr[0]);
    BAR; LGKM0;
    mfma_quad<0, 0>(afr, bfr[0], acc);
    BAR; MEMPIN;

    load_b(B1, b_base, 1, bfr[1]);
    BAR; LGKM0;
    mfma_quad<0, 1>(afr, bfr[1], acc);
    BAR; MEMPIN;

    load_a(A1, a_base, 1, afr);
    if (so) stage_half(sB3, B1, 0, w, lane);
    BAR; LGKM0;
    mfma_quad<1, 0>(afr, bfr[0], acc);
    BAR; MEMPIN;

    if (so) stage_half(sB3, B1, 1, w, lane);
    BAR; LGKM0;
    mfma_quad<1, 1>(afr, bfr[1], acc);
    if (i < 3) { VMCNT(4); } else { VMCNT(0); }
    BAR; MEMPIN;
  }

  // ---- epilogue: +b2, per-wave LDS transpose, non-temporal full-line stores ----
  // After the final barrier no wave touches main-loop LDS; each wave uses its
  // private slice (16 rows x 68 f32 = 4352 B).
  float* lslice = (float*)(smem + w * 4352);
  const size_t orow0 = (size_t)my * 256 + wm * 128;
  const int ncol0 = ny * 256 + wn * 64;
  float bv[4];
#pragma unroll
  for (int ni4 = 0; ni4 < 4; ++ni4) bv[ni4] = b2[ncol0 + ni4 * 16 + fr];

  const int rrow = lane >> 4;          // reader row within 4-row group
  const int rcol = (lane & 15) * 4;    // reader col (f32)
#pragma unroll
  for (int mi8 = 0; mi8 < 8; ++mi8) {
    // scatter acc into LDS at out-layout positions (<=2-way banks)
#pragma unroll
    for (int ni4 = 0; ni4 < 4; ++ni4)
#pragma unroll
      for (int r = 0; r < 4; ++r)
        lslice[(fq * 4 + r) * 68 + ni4 * 16 + fr] = acc[mi8][ni4][r] + bv[ni4];
    // gather rows, store 16B/lane (1024B/instr, full HBM lines), nt
#pragma unroll
    for (int j = 0; j < 4; ++j) {
      int row = j * 4 + rrow;
      f32x4 v = *(const f32x4*)&lslice[row * 68 + rcol];
      __builtin_nontemporal_store(
          v, (f32x4*)&out[(orow0 + mi8 * 16 + row) * 2048 + ncol0 + rcol]);
    }
  }
}

extern "C" void kernel_launch(void* const* d_in, const int* in_sizes, int n_in,
                              void* d_out, int out_size, void* d_ws, size_t ws_size,
                              hipStream_t stream) {
  const float* enc = (const float*)d_in[0];
  const float* dec = (const float*)d_in[1];
  const float* W1  = (const float*)d_in[2];
  const float* b1  = (const float*)d_in[3];
  const float* W2  = (const float*)d_in[4];
  const float* b2  = (const float*)d_in[5];
  float* out = (float*)d_out;

  char* ws = (char*)d_ws;
  float* enc_proj = (float*)ws;                                    // 2 MB
  unsigned short* decb = (unsigned short*)(ws + (2u << 20));       // 512 KB
  unsigned short* W2t  = (unsigned short*)(ws + (2u << 20) + (512u << 10)); // 2 MB
  unsigned short* Hbuf = (unsigned short*)(ws + (8u << 20));       // 134.25 MB

  proj8_kernel<<<192, 512, 0, stream>>>(enc, dec, W1, b1, enc_proj, decb);
  w2t_kernel<<<dim3(64, 16), 256, 0, stream>>>(W2, W2t);
  h_kernel<<<32768, 256, 0, stream>>>(enc_proj, decb, Hbuf);
  gemm8_kernel<<<4096, 512, 0, stream>>>(Hbuf, W2t, b2, out);
}

// Round 6
// 406.051 us; speedup vs baseline: 1.8769x; 1.0516x over previous
//
#include <hip/hip_runtime.h>
#include <hip/hip_bf16.h>

// Transducer joint: logits[b,t,u,v] = tanh(enc_proj[b,t,:]+dec_proj[b,u,:]+b1) @ W2 + b2
// B=4 T=256 U=128, ENC=DEC=512, INNER=512, VOCAB=2048
// R6: gemm re-tiled for 2 blocks/CU (epilogue/loop overlap): BM=256 BN=128
//     BK=32, ring-3 LDS (72 KB), 8 waves of 64x64, 16 single-barrier phases,
//     counted vmcnt(3), XOR-swizzled LDS, nt epilogue stores.

typedef __attribute__((ext_vector_type(4))) float f32x4;
typedef __attribute__((ext_vector_type(8))) __bf16 bf16x8;
typedef __attribute__((ext_vector_type(8))) unsigned short u16x8;

__device__ __forceinline__ float bf2f(unsigned short u) {
  unsigned int x = ((unsigned int)u) << 16;
  return __builtin_bit_cast(float, x);
}
__device__ __forceinline__ unsigned short f2bf(float f) {
  unsigned int x = __builtin_bit_cast(unsigned int, f);
  x += 0x7fff + ((x >> 16) & 1);   // RNE
  return (unsigned short)(x >> 16);
}
__device__ __forceinline__ float tanh_fast(float x) {
  float e = __expf(2.0f * x);
  return 1.0f - 2.0f * __builtin_amdgcn_rcpf(e + 1.0f);
}

typedef __attribute__((address_space(3))) unsigned int lds_u32;
typedef const __attribute__((address_space(1))) unsigned int glb_u32;
__device__ __forceinline__ void gl16(const void* g, void* l) {
  __builtin_amdgcn_global_load_lds((glb_u32*)g, (lds_u32*)l, 16, 0, 0);
}

#define BAR __builtin_amdgcn_s_barrier()
#define LGKM0 asm volatile("s_waitcnt lgkmcnt(0)" ::: "memory")
#define VMCNT(n) asm volatile("s_waitcnt vmcnt(" #n ")" ::: "memory")
#define MEMPIN asm volatile("" ::: "memory")

// ---------------- Pass 1: proj (x-in-LDS broadcast GEMM) ----------------
__global__ __launch_bounds__(512) void proj8_kernel(
    const float* __restrict__ enc, const float* __restrict__ dec,
    const float* __restrict__ W1, const float* __restrict__ b1,
    float* __restrict__ enc_proj, unsigned short* __restrict__ decb) {
  __shared__ float xs[8][512];
  const int bid = blockIdx.x;
  const bool isenc = bid < 128;
  const int rows0 = (isenc ? bid : bid - 128) * 8;
  const float* src = (isenc ? enc : dec) + (size_t)rows0 * 512;
  const int tid = threadIdx.x;
#pragma unroll
  for (int j = 0; j < 2; ++j) {
    int v = j * 512 + tid;
    int row = v >> 7;
    int c4 = (v & 127) << 2;
    *(f32x4*)&xs[row][c4] = *(const f32x4*)&src[(size_t)row * 512 + c4];
  }
  __syncthreads();
  const int h = tid;
  const float* wp = W1 + (isenc ? 0 : (size_t)512 * 512) + h;
  float acc[8];
  float init = isenc ? 0.f : b1[h];
#pragma unroll
  for (int r = 0; r < 8; ++r) acc[r] = init;
#pragma unroll 4
  for (int k = 0; k < 512; ++k) {
    float wv = wp[(size_t)k * 512];
#pragma unroll
    for (int r = 0; r < 8; ++r) acc[r] = fmaf(xs[r][k], wv, acc[r]);
  }
  if (isenc) {
#pragma unroll
    for (int r = 0; r < 8; ++r) enc_proj[(size_t)(rows0 + r) * 512 + h] = acc[r];
  } else {
#pragma unroll
    for (int r = 0; r < 8; ++r) decb[(size_t)(rows0 + r) * 512 + h] = f2bf(acc[r]);
  }
}

// ---------------- Pass 2: W2 [512][2048] fp32 -> W2t [2048][512] bf16 ----------------
__global__ __launch_bounds__(256) void w2t_kernel(const float* __restrict__ W2,
                                                  unsigned short* __restrict__ W2t) {
  __shared__ unsigned short tile[32][33];
  int bn = blockIdx.x;
  int bk = blockIdx.y;
  int tx = threadIdx.x & 31;
  int ty = threadIdx.x >> 5;
#pragma unroll
  for (int i = 0; i < 32; i += 8)
    tile[ty + i][tx] = f2bf(W2[(size_t)(bk * 32 + ty + i) * 2048 + bn * 32 + tx]);
  __syncthreads();
#pragma unroll
  for (int i = 0; i < 32; i += 8)
    W2t[(size_t)(bn * 32 + ty + i) * 512 + bk * 32 + tx] = tile[tx][ty + i];
}

// ---------------- Pass 3: H[m][h] = tanh(encp[bt][h] + decb[bu][h]) bf16 ----------------
__global__ __launch_bounds__(256) void h_kernel(
    const float* __restrict__ encp, const unsigned short* __restrict__ decb,
    unsigned short* __restrict__ Hout) {
  int gid = blockIdx.x * 256 + threadIdx.x;
  int m = gid >> 6;
  int hc = (gid & 63) << 3;
  int bt = m >> 7;
  int bu = ((m >> 15) << 7) | (m & 127);
  u16x8 dv = *(const u16x8*)(decb + (size_t)bu * 512 + hc);
  f32x4 e0 = *(const f32x4*)(encp + (size_t)bt * 512 + hc);
  f32x4 e1 = *(const f32x4*)(encp + (size_t)bt * 512 + hc + 4);
  u16x8 hv;
#pragma unroll
  for (int j = 0; j < 4; ++j) hv[j] = f2bf(tanh_fast(bf2f(dv[j]) + e0[j]));
#pragma unroll
  for (int j = 0; j < 4; ++j) hv[4 + j] = f2bf(tanh_fast(bf2f(dv[4 + j]) + e1[j]));
  *(u16x8*)(Hout + (size_t)m * 512 + hc) = hv;
}

// ---------------- Pass 4: BM=256 BN=128 BK=32 ring-3 GEMM ----------------
// LDS per slot: A [256][32] bf16 (16 KB) + B [128][32] bf16 (8 KB) = 24 KB;
// 3 slots = 72 KB -> 2 blocks/CU. 8 waves (4M x 2N), wave-tile 64x64,
// acc 64 VGPR, __launch_bounds__(512,4) -> 4 waves/SIMD.
// Swizzle: LDS[r][c16] holds src[r][(c16 ^ (r&3))] (16B chunks); read addr
// col = (fq ^ (r&3)) -> 2-way banks max.
// Phase t: vmcnt(3) [batch t done; batch t+1 in flight] -> barrier ->
// ds_read 8 -> stage batch t+2 (3 gl16) -> lgkm -> 16 MFMA.

__global__ __launch_bounds__(512, 4) void gemm32_kernel(
    const unsigned short* __restrict__ H,     // [131072][512] bf16
    const unsigned short* __restrict__ W2t,   // [2048][512] bf16
    const float* __restrict__ b2,             // [2048]
    float* __restrict__ out) {                // [131072][2048] fp32
  __shared__ __align__(1024) char smem[73728];

  const int bid = blockIdx.x;
  const int wg = (bid & 7) * 1024 + (bid >> 3);  // 8192%8==0 -> bijective
  const int my = wg >> 4;    // 0..511 (A panel; 16 consecutive wg share it)
  const int ny = wg & 15;    // 0..15

  const int tid = threadIdx.x;
  const int lane = tid & 63;
  const int w = tid >> 6;    // 0..7
  const int wm = w >> 1;     // 0..3
  const int wn = w & 1;      // 0..1
  const int fr = lane & 15;
  const int fq = lane >> 4;

  const char* ha = (const char*)(H + (size_t)my * 256 * 512);    // panel, row=1024B
  const char* wb = (const char*)(W2t + (size_t)ny * 128 * 512);  // panel, row=1024B

  // per-thread gl16 source offsets (dest is linear: p*8192 + w*1024 + lane*16)
  size_t srcA[2], srcB;
#pragma unroll
  for (int p = 0; p < 2; ++p) {
    int d = p * 8192 + w * 1024 + lane * 16;
    int r = d >> 6;
    int c = (d >> 4) & 3;
    srcA[p] = (size_t)r * 1024 + (size_t)((c ^ (r & 3)) << 4);
  }
  {
    int d = w * 1024 + lane * 16;
    int r = d >> 6;
    int c = (d >> 4) & 3;
    srcB = (size_t)r * 1024 + (size_t)((c ^ (r & 3)) << 4);
  }

  // ds_read offsets (within slot)
  const int swz = (fq ^ (fr & 3)) << 4;
  const int ldsA = (wm * 64 + fr) * 64 + swz;            // + mi*1024
  const int ldsB = 16384 + (wn * 64 + fr) * 64 + swz;    // + ni*1024

  f32x4 acc[4][4];
#pragma unroll
  for (int i = 0; i < 4; ++i)
#pragma unroll
    for (int j = 0; j < 4; ++j) acc[i][j] = (f32x4){0.f, 0.f, 0.f, 0.f};

#define STAGE(tt, slot)                                         \
  do {                                                          \
    char* sl = smem + (slot)*24576;                             \
    gl16(ha + srcA[0] + (tt)*64, sl + w * 1024);                \
    gl16(ha + srcA[1] + (tt)*64, sl + 8192 + w * 1024);         \
    gl16(wb + srcB + (tt)*64, sl + 16384 + w * 1024);           \
  } while (0)

  // prologue: batch 0 -> slot 0, batch 1 -> slot 1
  STAGE(0, 0);
  STAGE(1, 1);

#pragma unroll
  for (int t = 0; t < 16; ++t) {
    if (t < 15) { VMCNT(3); } else { VMCNT(0); }
    BAR; MEMPIN;
    const char* As = smem + (t % 3) * 24576;
    bf16x8 a4[4], b4[4];
#pragma unroll
    for (int mi = 0; mi < 4; ++mi) a4[mi] = *(const bf16x8*)(As + ldsA + mi * 1024);
#pragma unroll
    for (int ni = 0; ni < 4; ++ni) b4[ni] = *(const bf16x8*)(As + ldsB + ni * 1024);
    if (t + 2 < 16) STAGE(t + 2, (t + 2) % 3);
    LGKM0;
    __builtin_amdgcn_s_setprio(1);
#pragma unroll
    for (int mi = 0; mi < 4; ++mi)
#pragma unroll
      for (int ni = 0; ni < 4; ++ni)
        acc[mi][ni] = __builtin_amdgcn_mfma_f32_16x16x32_bf16(
            a4[mi], b4[ni], acc[mi][ni], 0, 0, 0);
    __builtin_amdgcn_s_setprio(0);
  }
  BAR; MEMPIN;   // protect epilogue LDS reuse

  // ---- epilogue: +b2, per-wave LDS transpose, nt stores (256B segments) ----
  float* lslice = (float*)(smem + w * 4352);   // 16 rows x 68 f32
  const size_t orow0 = (size_t)my * 256 + wm * 64;
  const int ncol0 = ny * 128 + wn * 64;
  float bv[4];
#pragma unroll
  for (int ni = 0; ni < 4; ++ni) bv[ni] = b2[ncol0 + ni * 16 + fr];

  const int rrow = lane >> 4;
  const int rcol = (lane & 15) * 4;
#pragma unroll
  for (int mi = 0; mi < 4; ++mi) {
#pragma unroll
    for (int ni = 0; ni < 4; ++ni)
#pragma unroll
      for (int r = 0; r < 4; ++r)
        lslice[(fq * 4 + r) * 68 + ni * 16 + fr] = acc[mi][ni][r] + bv[ni];
#pragma unroll
    for (int j = 0; j < 4; ++j) {
      int row = j * 4 + rrow;
      f32x4 v = *(const f32x4*)&lslice[row * 68 + rcol];
      __builtin_nontemporal_store(
          v, (f32x4*)&out[(orow0 + mi * 16 + row) * 2048 + ncol0 + rcol]);
    }
  }
#undef STAGE
}

extern "C" void kernel_launch(void* const* d_in, const int* in_sizes, int n_in,
                              void* d_out, int out_size, void* d_ws, size_t ws_size,
                              hipStream_t stream) {
  const float* enc = (const float*)d_in[0];
  const float* dec = (const float*)d_in[1];
  const float* W1  = (const float*)d_in[2];
  const float* b1  = (const float*)d_in[3];
  const float* W2  = (const float*)d_in[4];
  const float* b2  = (const float*)d_in[5];
  float* out = (float*)d_out;

  char* ws = (char*)d_ws;
  float* enc_proj = (float*)ws;                                    // 2 MB
  unsigned short* decb = (unsigned short*)(ws + (2u << 20));       // 512 KB
  unsigned short* W2t  = (unsigned short*)(ws + (2u << 20) + (512u << 10)); // 2 MB
  unsigned short* Hbuf = (unsigned short*)(ws + (8u << 20));       // 134.25 MB

  proj8_kernel<<<192, 512, 0, stream>>>(enc, dec, W1, b1, enc_proj, decb);
  w2t_kernel<<<dim3(64, 16), 256, 0, stream>>>(W2, W2t);
  h_kernel<<<32768, 256, 0, stream>>>(enc_proj, decb, Hbuf);
  gemm32_kernel<<<8192, 512, 0, stream>>>(Hbuf, W2t, b2, out);
}